// Round 4
// baseline (807.834 us; speedup 1.0000x reference)
//
#include <hip/hip_runtime.h>
#include <math.h>

// Problem constants
constexpr int NF  = 119;
constexpr int D1  = 422;
constexpr int D2  = 1170;

// Table offsets (float2 units) inside the TAB region
constexpr int OFF_W390  = 0;        // 390 : e^{-2pi i j/390}
constexpr int OFF_T1170 = 390;      // 1170: e^{+2pi i j/1170}
constexpr int OFF_W512  = 1560;     // 512 : e^{-2pi i j/512}
constexpr int OFF_CHIRP = 2072;     // 211 : W[n]=e^{+i pi n^2/211}
constexpr int OFF_U422  = 2283;     // 211 : e^{+2pi i p/422}
constexpr int OFF_BF    = 2494;     // 512 : FFT512(bwrap)/512
constexpr int OFF_T422  = 3006;     // 422 : e^{+2pi i j/422}

// GEMM geometry
constexpr int KP1 = 2368;           // stage1 K (2*1170 padded to 37*64)
constexpr int KB1 = KP1 * 2;        // 4736 bytes per A/B1t row
constexpr int KP2 = 448;            // stage2 K: concat(cos 224 | sin 224)
constexpr int KB2 = KP2 * 2;        // 896 bytes
constexpr int ZROW = 448;           // Z2 row (halves): [q][c*224 + k1]

// Scales: A = Y * 2^-10 ; y_true = y' * s, s = 1024/(422*1170)
constexpr float SC_A   = 9.765625e-4f;                 // 2^-10
constexpr double S_D   = 1024.0 / (422.0 * 1170.0);
constexpr float TH_CL  = (float)(1e-8 / (S_D * S_D));          // clamp in y'^2 domain
constexpr float FINAL  = (float)(S_D * S_D / (211.0 * 390.0)); // s^2 * mean scale

typedef _Float16 h16;
typedef _Float16 h16x2 __attribute__((ext_vector_type(2)));
typedef _Float16 h16x8 __attribute__((ext_vector_type(8)));
typedef float f32x4 __attribute__((ext_vector_type(4)));

__device__ inline float2 cmul(float2 a, float2 b) {
  return make_float2(fmaf(a.x, b.x, -(a.y * b.y)), fmaf(a.x, b.y, a.y * b.x));
}
__device__ inline float2 cmulc(float2 a, float2 b) {  // a * conj(b)
  return make_float2(fmaf(a.x, b.x, (a.y * b.y)), fmaf(a.y, b.x, -(a.x * b.y)));
}
__device__ inline void cfma(float2& c, float2 a, float2 b) {
  c.x = fmaf(a.x, b.x, fmaf(-a.y, b.y, c.x));
  c.y = fmaf(a.x, b.y, fmaf(a.y, b.x, c.y));
}

__device__ inline void async16(const void* g, void* l) {
  __builtin_amdgcn_global_load_lds((const __attribute__((address_space(1))) unsigned int*)g,
                                   (__attribute__((address_space(3))) unsigned int*)l, 16, 0, 0);
}

// In-place radix-2 FFT, 512 points, 256 threads per instance.
__device__ inline void fft512_lds(float2* a, const float2* w, int lt, int inv) {
  #pragma unroll
  for (int s = 0; s < 2; ++s) {
    int i = lt + (s << 8);
    int j = (int)(__brev((unsigned)i) >> 23);
    if (j > i) { float2 t = a[i]; a[i] = a[j]; a[j] = t; }
  }
  __syncthreads();
  for (int s = 1; s <= 9; ++s) {
    int half = 1 << (s - 1);
    int pos = lt & (half - 1);
    int grp = lt >> (s - 1);
    int i = (grp << s) + pos;
    int j = i + half;
    float2 tw = w[pos << (9 - s)];
    if (inv) tw.y = -tw.y;
    float2 t = cmul(a[j], tw);
    float2 ai = a[i];
    a[j] = make_float2(ai.x - t.x, ai.y - t.y);
    a[i] = make_float2(ai.x + t.x, ai.y + t.y);
    __syncthreads();
  }
}

__device__ inline void bluestein_core(float2* buf, const float2* w512s, const float2* __restrict__ Bt, int lt) {
  __syncthreads();
  fft512_lds(buf, w512s, lt, 0);
  #pragma unroll
  for (int s = 0; s < 2; ++s) { int i = lt + (s << 8); buf[i] = cmul(buf[i], Bt[i]); }
  __syncthreads();
  fft512_lds(buf, w512s, lt, 1);
}

// Three fused 390-point DFTs. 390 = 30 x 13. INV=1 => e^{+2pi i nk/390}.
template <int INV>
__device__ inline void dft390x3(const float2* a0, const float2* a1, const float2* a2,
                                float2* b0, float2* b1, float2* b2,
                                const float2* w, int tid,
                                float2& X0, float2& X1, float2& X2) {
  bool act = tid < 390;
  if (act) {
    int ka = tid % 30, nb = tid / 30;
    float2 c0 = make_float2(0.f, 0.f), c1 = c0, c2 = c0;
    int idx = 0, step = 13 * ka;
    #pragma unroll 6
    for (int na = 0; na < 30; ++na) {
      float2 tw = w[idx];
      if (INV) tw.y = -tw.y;
      int src = 13 * na + nb;
      cfma(c0, a0[src], tw);
      cfma(c1, a1[src], tw);
      cfma(c2, a2[src], tw);
      idx += step; if (idx >= 390) idx -= 390;
    }
    float2 t2 = w[nb * ka];
    if (INV) t2.y = -t2.y;
    int o = ka * 13 + nb;
    b0[o] = cmul(c0, t2);
    b1[o] = cmul(c1, t2);
    b2[o] = cmul(c2, t2);
  }
  __syncthreads();
  if (act) {
    int ka = tid % 30, kb = tid / 30;
    float2 c0 = make_float2(0.f, 0.f), c1 = c0, c2 = c0;
    int idx = 0, step = 30 * kb;
    #pragma unroll
    for (int nb = 0; nb < 13; ++nb) {
      float2 tw = w[idx];
      if (INV) tw.y = -tw.y;
      int src = ka * 13 + nb;
      cfma(c0, b0[src], tw);
      cfma(c1, b1[src], tw);
      cfma(c2, b2[src], tw);
      idx += step; if (idx >= 390) idx -= 390;
    }
    X0 = c0; X1 = c1; X2 = c2;
  }
  __syncthreads();
}

// ---------------- kernels ----------------

__global__ __launch_bounds__(512) void k_init(float2* __restrict__ tab, float* __restrict__ out) {
  int tid = threadIdx.x;
  __shared__ float2 bufE[512], bufO[512];
  __shared__ float2 w512s[512];
  __shared__ float2 chirps[211];
  const double PI = 3.14159265358979323846;
  for (int j = tid; j < 390; j += 512) {
    double a = -2.0 * PI * (double)j / 390.0; double s, c; sincos(a, &s, &c);
    tab[OFF_W390 + j] = make_float2((float)c, (float)s);
  }
  for (int j = tid; j < 1170; j += 512) {
    double a = 2.0 * PI * (double)j / 1170.0; double s, c; sincos(a, &s, &c);
    tab[OFF_T1170 + j] = make_float2((float)c, (float)s);
  }
  for (int j = tid; j < 422; j += 512) {
    double a = 2.0 * PI * (double)j / 422.0; double s, c; sincos(a, &s, &c);
    tab[OFF_T422 + j] = make_float2((float)c, (float)s);
  }
  for (int j = tid; j < 512; j += 512) {
    double a = -2.0 * PI * (double)j / 512.0; double s, c; sincos(a, &s, &c);
    float2 v = make_float2((float)c, (float)s);
    tab[OFF_W512 + j] = v; w512s[j] = v;
  }
  for (int n = tid; n < 211; n += 512) {
    int m = (n * n) % 422;
    double a = PI * (double)m / 211.0; double s, c; sincos(a, &s, &c);
    float2 v = make_float2((float)c, (float)s);
    tab[OFF_CHIRP + n] = v; chirps[n] = v;
  }
  for (int p = tid; p < 211; p += 512) {
    double a = 2.0 * PI * (double)p / 422.0; double s, c; sincos(a, &s, &c);
    tab[OFF_U422 + p] = make_float2((float)c, (float)s);
  }
  if (tid < NF) out[tid] = 0.0f;
  __syncthreads();
  int g = tid >> 8, lt = tid & 255;
  float2* buf = g ? bufO : bufE;
  #pragma unroll
  for (int s = 0; s < 2; ++s) {
    int i = lt + (s << 8);
    float2 v = make_float2(0.f, 0.f);
    if (i < 211) v = chirps[i];
    else if (i >= 302) v = chirps[512 - i];
    buf[i] = v;
  }
  __syncthreads();
  fft512_lds(buf, w512s, lt, 0);
  const float sc = 1.0f / 512.0f;
  if (g == 0) {
    #pragma unroll
    for (int s = 0; s < 2; ++s) {
      int i = lt + (s << 8);
      float2 v = buf[i];
      v.x *= sc; v.y *= sc;
      tab[OFF_BF + i] = v;
    }
  }
}

// Build B1t[n][k] fp16: n=2q+c (780 rows), k=2k2+ri (2368, zero-padded past 2340).
__global__ __launch_bounds__(256) void k_buildB(const float2* __restrict__ tab, h16* __restrict__ B1t) {
  int n = blockIdx.x;
  int q = n >> 1, c = n & 1;
  int tid = threadIdx.x;
  __shared__ float2 t[1170];
  for (int j = tid; j < 1170; j += 256) t[j] = tab[OFF_T1170 + j];
  __syncthreads();
  h16* row = B1t + (size_t)n * KP1;
  for (int k2 = tid; k2 < 1184; k2 += 256) {
    h16x2 h;
    if (k2 < 1170) {
      unsigned m = ((unsigned)q * (unsigned)k2) % 1170u;
      float2 e = t[m];
      h.x = (h16)(c ? e.y : e.x);
      h.y = (h16)(c ? e.x : -e.y);
    } else { h.x = (h16)0.f; h.y = (h16)0.f; }
    *(h16x2*)(row + 2 * k2) = h;
  }
}

// Build A2[p][k] fp16, concat layout: k<224 -> cf*cos, k>=224 -> -cf*sin. 256 rows (211 real).
__global__ __launch_bounds__(256) void k_buildA2(const float2* __restrict__ tab, h16* __restrict__ A2) {
  int p = blockIdx.x;   // [0,256)
  int tid = threadIdx.x;
  __shared__ float2 t[422];
  for (int j = tid; j < 422; j += 256) t[j] = tab[OFF_T422 + j];
  __syncthreads();
  h16* row = A2 + (size_t)p * KP2;
  for (int k = tid; k < KP2; k += 256) {
    int c = k / 224, k1 = k - c * 224;
    float v = 0.f;
    if (p < 211 && k1 < 212) {
      int m = (p * k1) % 422;
      float2 e = t[m];
      float cf = (k1 == 0 || k1 == 211) ? 1.f : 2.f;
      v = c ? (-cf * e.y) : (cf * e.x);
    }
    row[k] = (h16)v;
  }
}

// Forward row FFTs: rows of padded x -> length-1170 DFT via 3x pre-twiddled DFT-390.
__global__ __launch_bounds__(448) void k_rowfft(const float* __restrict__ x, const float2* __restrict__ tab,
                                                float2* __restrict__ X) {
  int i = blockIdx.x;  // < 211
  int tid = threadIdx.x;
  __shared__ float2 a0[390], a1[390], a2[390], b0[390], b1[390], b2[390];
  __shared__ float2 w390s[390];
  __shared__ float2 t1170s[780];
  for (int j = tid; j < 390; j += 448) w390s[j] = tab[OFF_W390 + j];
  for (int j = tid; j < 780; j += 448) t1170s[j] = tab[OFF_T1170 + j];
  __syncthreads();
  for (int j = tid; j < 390; j += 448) {
    float xv = 100.0f * x[i * 390 + j];
    a0[j] = make_float2(xv, 0.0f);
    float2 t1 = t1170s[j];
    a1[j] = make_float2(xv * t1.x, -xv * t1.y);
    float2 t2 = t1170s[2 * j];
    a2[j] = make_float2(xv * t2.x, -xv * t2.y);
  }
  __syncthreads();
  float2 X0 = make_float2(0,0), X1 = X0, X2 = X0;
  dft390x3<0>(a0, a1, a2, b0, b1, b2, w390s, tid, X0, X1, X2);
  if (tid < 390) {
    size_t base = (size_t)i * D2 + 3 * (size_t)tid;
    X[base + 0] = X0; X[base + 1] = X1; X[base + 2] = X2;
  }
}

// Forward column FFTs (8 per block) via 2x Bluestein-211. In-place in X.
__global__ __launch_bounds__(512) void k_colfft(const float2* __restrict__ tab, float2* __restrict__ X) {
  int tid = threadIdx.x;
  int q0 = blockIdx.x * 8;
  int ncols = min(8, D2 - q0);
  __shared__ float Xre[8][212], Xim[8][212];
  __shared__ float2 bufE[512], bufO[512];
  __shared__ float2 w512s[512], chirps[211], u422s[211];
  for (int j = tid; j < 512; j += 512) w512s[j] = tab[OFF_W512 + j];
  for (int j = tid; j < 211; j += 512) { chirps[j] = tab[OFF_CHIRP + j]; u422s[j] = tab[OFF_U422 + j]; }
  const float2* Bf = tab + OFF_BF;
  for (int idx = tid; idx < 211 * 8; idx += 512) {
    int i = idx >> 3, c = idx & 7;
    float2 v = make_float2(0.f, 0.f);
    if (c < ncols) v = X[(size_t)i * D2 + q0 + c];
    Xre[c][i] = v.x; Xim[c][i] = v.y;
  }
  __syncthreads();
  int g = tid >> 8, lt = tid & 255;
  float2* buf = g ? bufO : bufE;
  for (int c = 0; c < ncols; ++c) {
    #pragma unroll
    for (int s = 0; s < 2; ++s) {
      int i2 = lt + (s << 8);
      float2 v = make_float2(0.f, 0.f);
      if (i2 < 211) {
        v = make_float2(Xre[c][i2], Xim[c][i2]);
        if (g) v = cmulc(v, u422s[i2]);
        v = cmulc(v, chirps[i2]);
      }
      buf[i2] = v;
    }
    bluestein_core(buf, w512s, Bf, lt);
    #pragma unroll
    for (int s = 0; s < 2; ++s) {
      int i2 = lt + (s << 8);
      if (i2 < 211) {
        float2 r = cmulc(buf[i2], chirps[i2]);
        X[(size_t)(2 * i2 + g) * D2 + q0 + c] = r;
      }
    }
    __syncthreads();
  }
}

// Build A (stage1 GEMM LHS): A[fl][k1][2k2+ri] = (X[k1]*G_f[k1])*2^-10 fp16.
__global__ __launch_bounds__(256) void k_buildA(const float* __restrict__ Hr, const float* __restrict__ Hi,
                                                const float2* __restrict__ X, h16* __restrict__ A, int f0) {
  int k1 = blockIdx.x, fl = blockIdx.y, f = f0 + fl;
  int tid = threadIdx.x;
  int m1 = (422 - k1) % 422;
  size_t hb  = (size_t)f * (D1 * D2) + (size_t)k1 * D2;
  size_t hmb = (size_t)f * (D1 * D2) + (size_t)m1 * D2;
  const float2* Xr = X + (size_t)k1 * D2;
  h16* Arow = A + ((size_t)fl * 212 + k1) * KP1;
  for (int k2 = tid; k2 < 1170; k2 += 256) {
    int rk = k2 ? 1170 - k2 : 0;
    float gr = 0.5f * (Hr[hb + k2] + Hr[hmb + rk]);
    float gi = 0.5f * (Hi[hb + k2] - Hi[hmb + rk]);
    float2 xv = Xr[k2];
    float yr = (xv.x * gr - xv.y * gi) * SC_A;
    float yi = (xv.x * gi + xv.y * gr) * SC_A;
    h16x2 h; h.x = (h16)yr; h.y = (h16)yi;
    *(h16x2*)(Arow + 2 * k2) = h;
  }
  if (tid < 28) Arow[2340 + tid] = (h16)0.f;
}

// Stage1 MFMA GEMM: Z2[q][c*224+k1] = (A[212 x 2368] * B1t^T)[k1][2q+c].
// Block 256 thr / 4 waves 2x2, tile 128x128, BK=64 (37 iters). XCD-swizzled grid:
// all 14 tiles of a filter share blockIdx%8 -> same XCD (round-robin heuristic).
__global__ __launch_bounds__(256) void k_gemm1(const h16* __restrict__ A, const h16* __restrict__ B1t,
                                               h16* __restrict__ Z2, int nf) {
  int id = blockIdx.x;
  int r8 = id & 7;
  int t14 = (id >> 3) % 14;
  int g8 = (id >> 3) / 14;
  int fl = r8 + (g8 << 3);
  if (fl >= nf) return;
  int mt = t14 / 7, nt = t14 % 7;
  const int M0 = mt ? 84 : 0;
  const int N0 = (nt == 6) ? 652 : nt * 128;
  int tid = threadIdx.x, wv = tid >> 6, ln = tid & 63;
  int l15 = ln & 15, l16 = ln >> 4;
  int wm = (wv >> 1) * 64, wn = (wv & 1) * 64;
  __shared__ __align__(16) h16 Alds[128 * 64];   // 16 KB, row = 128 B
  __shared__ __align__(16) h16 Blds[128 * 64];
  const char* Ag = (const char*)(A + (size_t)fl * 212 * KP1);
  const char* Bg = (const char*)B1t;
  f32x4 acc[4][4] = {};
  for (int kc = 0; kc < 37; ++kc) {
    int kb = kc * 128;
    __syncthreads();
    #pragma unroll
    for (int s = 0; s < 4; ++s) {
      int idx = s * 256 + tid;
      int row = idx >> 3, colb = (idx & 7) * 16;
      async16(Ag + (size_t)(M0 + row) * KB1 + kb + colb, (char*)Alds + idx * 16);
      async16(Bg + (size_t)(N0 + row) * KB1 + kb + colb, (char*)Blds + idx * 16);
    }
    __syncthreads();
    const h16x8* Av = (const h16x8*)Alds;
    const h16x8* Bv = (const h16x8*)Blds;
    #pragma unroll
    for (int h = 0; h < 2; ++h) {
      h16x8 af[4], bf[4];
      #pragma unroll
      for (int i = 0; i < 4; ++i) af[i] = Av[(wm + i * 16 + l15) * 8 + (h << 2) + l16];
      #pragma unroll
      for (int j = 0; j < 4; ++j) bf[j] = Bv[(wn + j * 16 + l15) * 8 + (h << 2) + l16];
      #pragma unroll
      for (int i = 0; i < 4; ++i)
        #pragma unroll
        for (int j = 0; j < 4; ++j)
          acc[i][j] = __builtin_amdgcn_mfma_f32_16x16x32_f16(af[i], bf[j], acc[i][j], 0, 0, 0);
    }
  }
  h16* Zf = Z2 + (size_t)fl * 390 * ZROW;
  #pragma unroll
  for (int i = 0; i < 4; ++i) {
    #pragma unroll
    for (int j = 0; j < 4; ++j) {
      #pragma unroll
      for (int r = 0; r < 4; ++r) {
        int m = M0 + wm + i * 16 + l16 * 4 + r;
        if (m < 212) {
          int n = N0 + wn + j * 16 + l15;
          int q = n >> 1, c = n & 1;
          Zf[(size_t)q * ZROW + c * 224 + m] = (h16)acc[i][j][r];
        }
      }
    }
  }
}

// Stage2 MFMA GEMM + fused power-mean epilogue. Plain GEMM: y'[p][q] = sum_k A2[p][k]*Z2[q][k].
// Block 512 thr / 8 waves 4x2, tile 256x128, K=448 (14 iters of BK=32). XCD-swizzled like gemm1.
__global__ __launch_bounds__(512) void k_gemm2(const h16* __restrict__ A2, const h16* __restrict__ Z2,
                                               float* __restrict__ out, int f0, int nf) {
  int id = blockIdx.x;
  int r8 = id & 7;
  int nt = (id >> 3) & 3;
  int g8 = (id >> 3) >> 2;
  int fl = r8 + (g8 << 3);
  if (fl >= nf) return;
  int f = f0 + fl;
  const int N0 = (nt == 3) ? 262 : nt * 128;
  const int qmin = (nt == 3) ? 384 : 0;
  int tid = threadIdx.x, wv = tid >> 6, ln = tid & 63;
  int l15 = ln & 15, l16 = ln >> 4;
  int wm = (wv >> 1) * 64, wn = (wv & 1) * 64;
  __shared__ __align__(16) h16 Alds[256 * 32];   // 16 KB
  __shared__ __align__(16) h16 Blds[128 * 32];   // 8 KB
  const char* Ag = (const char*)A2;
  const char* Bg = (const char*)(Z2 + (size_t)fl * 390 * ZROW);
  f32x4 acc[4][4] = {};
  for (int kc = 0; kc < 14; ++kc) {
    int kb = kc * 64;
    __syncthreads();
    #pragma unroll
    for (int s = 0; s < 2; ++s) {
      int idx = s * 512 + tid;
      int row = idx >> 2, colb = (idx & 3) * 16;
      async16(Ag + (size_t)row * KB2 + kb + colb, (char*)Alds + idx * 16);
    }
    {
      int row = tid >> 2, colb = (tid & 3) * 16;
      async16(Bg + (size_t)(N0 + row) * KB2 + kb + colb, (char*)Blds + tid * 16);
    }
    __syncthreads();
    const h16x8* Av = (const h16x8*)Alds;
    const h16x8* Bv = (const h16x8*)Blds;
    h16x8 af[4], bf[4];
    #pragma unroll
    for (int i = 0; i < 4; ++i) af[i] = Av[(wm + i * 16 + l15) * 4 + l16];
    #pragma unroll
    for (int j = 0; j < 4; ++j) bf[j] = Bv[(wn + j * 16 + l15) * 4 + l16];
    #pragma unroll
    for (int i = 0; i < 4; ++i)
      #pragma unroll
      for (int j = 0; j < 4; ++j)
        acc[i][j] = __builtin_amdgcn_mfma_f32_16x16x32_f16(af[i], bf[j], acc[i][j], 0, 0, 0);
  }
  float accs = 0.f;
  #pragma unroll
  for (int i = 0; i < 4; ++i) {
    #pragma unroll
    for (int j = 0; j < 4; ++j) {
      #pragma unroll
      for (int r = 0; r < 4; ++r) {
        int p = wm + i * 16 + l16 * 4 + r;
        int q = N0 + wn + j * 16 + l15;
        if (p < 211 && q < 390 && q >= qmin) {
          float y = acc[i][j][r];
          accs += fmaxf(y * y, TH_CL);
        }
      }
    }
  }
  for (int off = 32; off > 0; off >>= 1) accs += __shfl_down(accs, off, 64);
  __shared__ float wred[8];
  if (ln == 0) wred[wv] = accs;
  __syncthreads();
  if (tid == 0) {
    float tot = 0.f;
    #pragma unroll
    for (int w = 0; w < 8; ++w) tot += wred[w];
    atomicAdd(&out[f], tot * FINAL);
  }
}

extern "C" void kernel_launch(void* const* d_in, const int* in_sizes, int n_in,
                              void* d_out, int out_size, void* d_ws, size_t ws_size,
                              hipStream_t stream) {
  const float* x  = (const float*)d_in[0];
  const float* Hr = (const float*)d_in[1];
  const float* Hi = (const float*)d_in[2];
  float* out = (float*)d_out;
  char* base = (char*)d_ws;

  size_t off = 0;
  auto alloc = [&](size_t bytes) { size_t cur = off; off = (off + bytes + 255) & ~(size_t)255; return cur; };
  float2* tab = (float2*)(base + alloc(32768));
  float2* X   = (float2*)(base + alloc((size_t)D1 * D2 * sizeof(float2)));
  h16* B1t    = (h16*)(base + alloc((size_t)780 * KP1 * 2));
  h16* A2     = (h16*)(base + alloc((size_t)256 * KP2 * 2));
  size_t perA = (size_t)212 * KP1 * 2;   // 1,004,032 B
  size_t perZ = (size_t)390 * ZROW * 2;  //   349,440 B
  long long avail = (long long)ws_size - (long long)off - 512;
  int chunk = (avail > 0) ? (int)(avail / (long long)(perA + perZ)) : 1;
  if (chunk < 1) chunk = 1;
  if (chunk > NF) chunk = NF;
  h16* A  = (h16*)(base + alloc(perA * chunk));
  h16* Zp = (h16*)(base + alloc(perZ * chunk));

  k_init<<<dim3(1), dim3(512), 0, stream>>>(tab, out);
  k_buildB<<<dim3(780), dim3(256), 0, stream>>>(tab, B1t);
  k_buildA2<<<dim3(256), dim3(256), 0, stream>>>(tab, A2);
  k_rowfft<<<dim3(211), dim3(448), 0, stream>>>(x, tab, X);
  k_colfft<<<dim3(147), dim3(512), 0, stream>>>(tab, X);
  for (int f0 = 0; f0 < NF; f0 += chunk) {
    int nf = NF - f0;
    if (nf > chunk) nf = chunk;
    int ngrp = (nf + 7) / 8;
    k_buildA<<<dim3(212, nf), dim3(256), 0, stream>>>(Hr, Hi, X, A, f0);
    k_gemm1<<<dim3(8 * 14 * ngrp), dim3(256), 0, stream>>>(A, B1t, Zp, nf);
    k_gemm2<<<dim3(8 * 4 * ngrp), dim3(512), 0, stream>>>(A2, Zp, out, f0, nf);
  }
}